// Round 1
// baseline (36.915 us; speedup 1.0000x reference)
//
#include <hip/hip_runtime.h>

namespace {

constexpr int CH  = 8;     // hidden/out channels
constexpr int CIN = 8;     // feature channels
constexpr int HH  = 100;
constexpr int WW  = 136;
constexpr int HW  = HH * WW;   // 13600
constexpr int NP  = 232;       // params per instance: 80 + 64 + 64 + 8+8+8
constexpr int VP  = 4;         // pixels per thread (float4)
constexpr int BLK = 256;

// param layout per instance:
//  w1[o][i] = p[o*10 + i]        o<8, i<10  (i=0: rel_x, i=1: rel_y, i=2+c: feat c)
//  w2[o][i] = p[80  + o*8 + i]
//  w3[o][i] = p[144 + o*8 + i]
//  b1[o]    = p[208 + o]
//  b2[o]    = p[216 + o]
//  b3[o]    = p[224 + o]

__global__ __launch_bounds__(BLK)
void dmh_kernel(const float* __restrict__ feats,     // (N_IMG, CIN, HW)
                const float* __restrict__ params,    // (n_inst, NP)
                const float* __restrict__ ilocs,     // (n_inst, 2)
                const int*   __restrict__ im_inds,   // (n_inst)
                const int*   __restrict__ lvls,      // (n_inst)
                const int*   __restrict__ stride_p,  // (1)
                float*       __restrict__ out)       // (n_inst, CH, HW)
{
    const int n   = blockIdx.y;
    const int tid = threadIdx.x;

    __shared__ float sp[NP];
    if (tid < NP) sp[tid] = params[(size_t)n * NP + tid];
    __syncthreads();

    const int p0 = (blockIdx.x * BLK + tid) * VP;
    if (p0 >= HW) return;

    // per-instance uniforms
    const int   im  = im_inds[n];
    const int   lvl = lvls[n];
    const float soi_tab[5] = {64.f, 128.f, 256.f, 512.f, 1024.f};
    const float inv_soi = 1.0f / soi_tab[lvl];
    const float ix = ilocs[2 * n + 0];
    const float iy = ilocs[2 * n + 1];

    // stride scalar: tolerate int32 or float32 encoding
    const int   s_i = stride_p[0];
    const float fs  = (s_i >= 1 && s_i <= 65536) ? (float)s_i : __int_as_float(s_i);
    const float fh  = floorf(fs * 0.5f);   // stride // 2

    // load 8 feature channels x 4 pixels (float4, coalesced; L2-resident)
    float f[CIN][VP];
    const float* fbase = feats + (size_t)im * CIN * HW + p0;
    #pragma unroll
    for (int c = 0; c < CIN; ++c) {
        const float4 v = *reinterpret_cast<const float4*>(fbase + c * HW);
        f[c][0] = v.x; f[c][1] = v.y; f[c][2] = v.z; f[c][3] = v.w;
    }

    // relative coordinates
    float relx[VP], rely[VP];
    #pragma unroll
    for (int j = 0; j < VP; ++j) {
        const int p = p0 + j;
        const int y = p / WW;
        const int x = p - y * WW;
        relx[j] = (ix - ((float)x * fs + fh)) * inv_soi;
        rely[j] = (iy - ((float)y * fs + fh)) * inv_soi;
    }

    // layer 1: 10 -> 8, ReLU
    float h1[CH][VP];
    #pragma unroll
    for (int o = 0; o < CH; ++o) {
        const float w0 = sp[o * 10 + 0];
        const float w1 = sp[o * 10 + 1];
        const float b  = sp[208 + o];
        #pragma unroll
        for (int j = 0; j < VP; ++j) {
            float a = fmaf(w0, relx[j], fmaf(w1, rely[j], b));
            #pragma unroll
            for (int c = 0; c < CIN; ++c)
                a = fmaf(sp[o * 10 + 2 + c], f[c][j], a);
            h1[o][j] = fmaxf(a, 0.f);
        }
    }

    // layer 2: 8 -> 8, ReLU
    float h2[CH][VP];
    #pragma unroll
    for (int o = 0; o < CH; ++o) {
        const float b = sp[216 + o];
        #pragma unroll
        for (int j = 0; j < VP; ++j) {
            float a = b;
            #pragma unroll
            for (int i = 0; i < CH; ++i)
                a = fmaf(sp[80 + o * 8 + i], h1[i][j], a);
            h2[o][j] = fmaxf(a, 0.f);
        }
    }

    // layer 3: 8 -> 8, ReLU
    float h3[CH][VP];
    #pragma unroll
    for (int o = 0; o < CH; ++o) {
        const float b = sp[224 + o];
        #pragma unroll
        for (int j = 0; j < VP; ++j) {
            float a = b;
            #pragma unroll
            for (int i = 0; i < CH; ++i)
                a = fmaf(sp[144 + o * 8 + i], h2[i][j], a);
            h3[o][j] = fmaxf(a, 0.f);
        }
    }

    // store 8 channels x 4 pixels (float4, coalesced)
    float* ob = out + (size_t)n * CH * HW + p0;
    #pragma unroll
    for (int o = 0; o < CH; ++o) {
        float4 v;
        v.x = h3[o][0]; v.y = h3[o][1]; v.z = h3[o][2]; v.w = h3[o][3];
        *reinterpret_cast<float4*>(ob + o * HW) = v;
    }
}

} // namespace

extern "C" void kernel_launch(void* const* d_in, const int* in_sizes, int n_in,
                              void* d_out, int out_size, void* d_ws, size_t ws_size,
                              hipStream_t stream) {
    const float* feats  = (const float*)d_in[0];
    const float* params = (const float*)d_in[1];
    const float* ilocs  = (const float*)d_in[2];
    const int*   im     = (const int*)d_in[3];
    const int*   lv     = (const int*)d_in[4];
    const int*   st     = (const int*)d_in[5];
    float*       out    = (float*)d_out;

    const int n_inst = in_sizes[1] / NP;   // 400
    dim3 grid((HW + BLK * VP - 1) / (BLK * VP), n_inst);
    dmh_kernel<<<grid, BLK, 0, stream>>>(feats, params, ilocs, im, lv, st, out);
}